// Round 1
// baseline (1271.775 us; speedup 1.0000x reference)
//
#include <hip/hip_runtime.h>

#define HID 64

// ---------------- degree / norm ----------------
__global__ void k_init_deg(float* deg, int n) {
  int i = blockIdx.x * blockDim.x + threadIdx.x;
  if (i < n) deg[i] = 1.0f;  // self-loop
}

__global__ void k_count_deg(const int* __restrict__ dst, float* deg, int E) {
  int e = blockIdx.x * blockDim.x + threadIdx.x;
  if (e < E) atomicAdd(&deg[dst[e]], 1.0f);
}

__global__ void k_rsqrt(float* deg, int n) {
  int i = blockIdx.x * blockDim.x + threadIdx.x;
  if (i < n) deg[i] = rsqrtf(deg[i]);
}

// ---------------- node-level linear: Y[n,64] = X[n,K] @ W[K,64] ----------------
template <int K>
__global__ __launch_bounds__(256) void k_node_linear(const float* __restrict__ X,
                                                     const float* __restrict__ W,
                                                     float* __restrict__ Y, int n) {
  int r = blockIdx.x * blockDim.x + threadIdx.x;
  if (r >= n) return;
  float z[HID];
#pragma unroll
  for (int c = 0; c < HID; ++c) z[c] = 0.f;
  const float* xr = X + (long)r * K;
  for (int kc = 0; kc < K / 16; ++kc) {
    const float4* xp = (const float4*)(xr + kc * 16);
    float4 a0 = xp[0], a1 = xp[1], a2 = xp[2], a3 = xp[3];
    float ev[16] = {a0.x, a0.y, a0.z, a0.w, a1.x, a1.y, a1.z, a1.w,
                    a2.x, a2.y, a2.z, a2.w, a3.x, a3.y, a3.z, a3.w};
#pragma unroll
    for (int k = 0; k < 16; ++k) {
      const float* wr = W + (kc * 16 + k) * HID;  // wave-uniform -> s_load
      float ek = ev[k];
#pragma unroll
      for (int c = 0; c < HID; ++c) z[c] = fmaf(ek, wr[c], z[c]);
    }
  }
  float* yr = Y + (long)r * HID;
#pragma unroll
  for (int c = 0; c < HID; c += 4) {
    float4 v = {z[c], z[c + 1], z[c + 2], z[c + 3]};
    *(float4*)(yr + c) = v;
  }
}

// ---------------- aggregation ----------------
// A[n,c] = H[n,c] * dis[n]^2   (self-loop term, also initializes A)
__global__ void k_agg_self(const float* __restrict__ H, const float* __restrict__ dis,
                           float* __restrict__ A, int n) {
  long t = (long)blockIdx.x * blockDim.x + threadIdx.x;
  if (t >= (long)n * HID) return;
  int r = (int)(t >> 6);
  float d = dis[r];
  A[t] = H[t] * d * d;
}

// A[dst,c] += H[src,c] * dis[src]*dis[dst]   (one wave per edge: 64 channels)
__global__ void k_agg_edges(const float* __restrict__ H, const float* __restrict__ dis,
                            const int* __restrict__ src, const int* __restrict__ dst,
                            float* __restrict__ A, int E) {
  long t = (long)blockIdx.x * blockDim.x + threadIdx.x;
  if (t >= (long)E * HID) return;
  int e = (int)(t >> 6);
  int c = (int)(t & 63);
  int s = src[e];
  int d = dst[e];
  float w = dis[s] * dis[d];
  atomicAdd(&A[(long)d * HID + c], H[(long)s * HID + c] * w);
}

// A[n,c] = act(A[n,c] + b[c])
__global__ void k_bias_act(float* __restrict__ A, const float* __restrict__ b, int n,
                           int relu) {
  long t = (long)blockIdx.x * blockDim.x + threadIdx.x;
  if (t >= (long)n * HID) return;
  int c = (int)(t & 63);
  float v = A[t] + b[c];
  if (relu) v = fmaxf(v, 0.f);
  A[t] = v;
}

// ---------------- edge classifier ----------------
__device__ __forceinline__ void cls_accum(const float* __restrict__ er,
                                          const float* __restrict__ Wp,
                                          float* __restrict__ z) {
  for (int kc = 0; kc < 4; ++kc) {
    const float4* xp = (const float4*)(er + kc * 16);
    float4 a0 = xp[0], a1 = xp[1], a2 = xp[2], a3 = xp[3];
    float ev[16] = {a0.x, a0.y, a0.z, a0.w, a1.x, a1.y, a1.z, a1.w,
                    a2.x, a2.y, a2.z, a2.w, a3.x, a3.y, a3.z, a3.w};
#pragma unroll
    for (int k = 0; k < 16; ++k) {
      const float* wr = Wp + (kc * 16 + k) * HID;  // wave-uniform -> s_load
      float ek = ev[k];
#pragma unroll
      for (int c = 0; c < HID; ++c) z[c] = fmaf(ek, wr[c], z[c]);
    }
  }
}

__global__ __launch_bounds__(256) void k_classifier(
    const float* __restrict__ H, const int* __restrict__ src,
    const int* __restrict__ dst, const float* __restrict__ Wc1,
    const float* __restrict__ bc1, const float* __restrict__ Wc2,
    const float* __restrict__ bc2, float* __restrict__ out, int E) {
  int e = blockIdx.x * blockDim.x + threadIdx.x;
  if (e >= E) return;
  float z[HID];
#pragma unroll
  for (int c = 0; c < HID; ++c) z[c] = bc1[c];
  int s = src[e];
  int d = dst[e];
  cls_accum(H + (long)s * HID, Wc1, z);
  cls_accum(H + (long)d * HID, Wc1 + 64 * HID, z);
  float o0 = bc2[0], o1 = bc2[1];
#pragma unroll
  for (int c = 0; c < HID; ++c) {
    float zc = fmaxf(z[c], 0.f);
    o0 = fmaf(zc, Wc2[c * 2 + 0], o0);
    o1 = fmaf(zc, Wc2[c * 2 + 1], o1);
  }
  out[(long)e * 2 + 0] = o0;
  out[(long)e * 2 + 1] = o1;
}

// ---------------- launch ----------------
extern "C" void kernel_launch(void* const* d_in, const int* in_sizes, int n_in,
                              void* d_out, int out_size, void* d_ws, size_t ws_size,
                              hipStream_t stream) {
  const float* x   = (const float*)d_in[0];
  const int*   ei  = (const int*)d_in[1];
  const float* W1  = (const float*)d_in[2];
  const float* b1  = (const float*)d_in[3];
  const float* W2  = (const float*)d_in[4];
  const float* b2  = (const float*)d_in[5];
  const float* Wc1 = (const float*)d_in[6];
  const float* bc1 = (const float*)d_in[7];
  const float* Wc2 = (const float*)d_in[8];
  const float* bc2 = (const float*)d_in[9];

  const int N = in_sizes[0] / 128;
  const int E = in_sizes[1] / 2;
  const int* src = ei;
  const int* dst = ei + E;

  float* dis  = (float*)d_ws;         // N
  float* bufA = dis + N;              // N*64
  float* bufB = bufA + (long)N * HID; // N*64

  const int B = 256;
  int gN   = (N + B - 1) / B;
  int gE   = (E + B - 1) / B;
  long nc  = (long)N * HID;
  long ec  = (long)E * HID;
  int gNC  = (int)((nc + B - 1) / B);
  int gEC  = (int)((ec + B - 1) / B);

  // degree -> rsqrt
  k_init_deg<<<gN, B, 0, stream>>>(dis, N);
  k_count_deg<<<gE, B, 0, stream>>>(dst, dis, E);
  k_rsqrt<<<gN, B, 0, stream>>>(dis, N);

  // layer 1: h1 = x@W1 ; agg ; +b1 ; relu
  k_node_linear<128><<<gN, B, 0, stream>>>(x, W1, bufA, N);
  k_agg_self<<<gNC, B, 0, stream>>>(bufA, dis, bufB, N);
  k_agg_edges<<<gEC, B, 0, stream>>>(bufA, dis, src, dst, bufB, E);
  k_bias_act<<<gNC, B, 0, stream>>>(bufB, b1, N, 1);

  // layer 2: h2 = h1r@W2 ; agg ; +b2
  k_node_linear<64><<<gN, B, 0, stream>>>(bufB, W2, bufA, N);
  k_agg_self<<<gNC, B, 0, stream>>>(bufA, dis, bufB, N);
  k_agg_edges<<<gEC, B, 0, stream>>>(bufA, dis, src, dst, bufB, E);
  k_bias_act<<<gNC, B, 0, stream>>>(bufB, b2, N, 0);

  // edge classifier
  k_classifier<<<gE, B, 0, stream>>>(bufB, src, dst, Wc1, bc1, Wc2, bc2,
                                     (float*)d_out, E);
}

// Round 2
// 950.251 us; speedup vs baseline: 1.3384x; 1.3384x over previous
//
#include <hip/hip_runtime.h>

#define HID 64

// ---------------- utility ----------------
__global__ void k_zero_int(int* p, int n) {
  int i = blockIdx.x * blockDim.x + threadIdx.x;
  if (i < n) p[i] = 0;
}

// degree count (int atomics, excludes self-loop)
__global__ void k_count_deg(const int* __restrict__ dst, int* deg, int E) {
  int e = blockIdx.x * blockDim.x + threadIdx.x;
  if (e < E) atomicAdd(&deg[dst[e]], 1);
}

// dis = rsqrt(deg + 1)  (+1 self-loop)
__global__ void k_rsqrt_deg(const int* __restrict__ deg, float* dis, int n) {
  int i = blockIdx.x * blockDim.x + threadIdx.x;
  if (i < n) dis[i] = rsqrtf((float)deg[i] + 1.0f);
}

// ---------------- exclusive scan of deg -> rowoff (3-kernel) ----------------
// scan1: per-block (1024 elems) exclusive scan + block sum
__global__ void k_scan1(const int* __restrict__ deg, int* __restrict__ scanout,
                        int* __restrict__ blocksums, int n) {
  __shared__ int sdata[256];
  int tid = threadIdx.x;
  int base = blockIdx.x * 1024 + tid * 4;
  int v0 = 0, v1 = 0, v2 = 0, v3 = 0;
  if (base + 0 < n) v0 = deg[base + 0];
  if (base + 1 < n) v1 = deg[base + 1];
  if (base + 2 < n) v2 = deg[base + 2];
  if (base + 3 < n) v3 = deg[base + 3];
  int tsum = v0 + v1 + v2 + v3;
  sdata[tid] = tsum;
  __syncthreads();
  for (int off = 1; off < 256; off <<= 1) {
    int t = (tid >= off) ? sdata[tid - off] : 0;
    __syncthreads();
    sdata[tid] += t;
    __syncthreads();
  }
  int excl = sdata[tid] - tsum;
  if (base + 0 < n) scanout[base + 0] = excl;
  if (base + 1 < n) scanout[base + 1] = excl + v0;
  if (base + 2 < n) scanout[base + 2] = excl + v0 + v1;
  if (base + 3 < n) scanout[base + 3] = excl + v0 + v1 + v2;
  if (tid == 255) blocksums[blockIdx.x] = sdata[255];
}

// scan2: single block exclusive-scans the (<=128) block sums in place
__global__ void k_scan2(int* blocksums, int nb) {
  __shared__ int s[128];
  int tid = threadIdx.x;
  int v = (tid < nb) ? blocksums[tid] : 0;
  s[tid] = v;
  __syncthreads();
  for (int off = 1; off < 128; off <<= 1) {
    int t = (tid >= off) ? s[tid - off] : 0;
    __syncthreads();
    s[tid] += t;
    __syncthreads();
  }
  if (tid < nb) blocksums[tid] = s[tid] - v;
}

// scan3: add block offset; write rowoff and cursor copy
__global__ void k_scan3(const int* __restrict__ scanout,
                        const int* __restrict__ blocksums, int* __restrict__ rowoff,
                        int* __restrict__ cursor, int n) {
  int i = blockIdx.x * blockDim.x + threadIdx.x;
  if (i < n) {
    int v = scanout[i] + blocksums[i >> 10];
    rowoff[i] = v;
    cursor[i] = v;
  }
}

// scatter edges into CSR buckets by dst
__global__ void k_scatter(const int* __restrict__ src, const int* __restrict__ dst,
                          int* __restrict__ cursor, int* __restrict__ csr_src, int E) {
  int e = blockIdx.x * blockDim.x + threadIdx.x;
  if (e >= E) return;
  int d = dst[e];
  int pos = atomicAdd(&cursor[d], 1);
  csr_src[pos] = src[e];
}

// ---------------- node-level linear: Y[n,64] = X[n,K] @ W[K,64] ----------------
template <int K>
__global__ __launch_bounds__(256) void k_node_linear(const float* __restrict__ X,
                                                     const float* __restrict__ W,
                                                     float* __restrict__ Y, int n) {
  int r = blockIdx.x * blockDim.x + threadIdx.x;
  if (r >= n) return;
  float z[HID];
#pragma unroll
  for (int c = 0; c < HID; ++c) z[c] = 0.f;
  const float* xr = X + (long)r * K;
  for (int kc = 0; kc < K / 16; ++kc) {
    const float4* xp = (const float4*)(xr + kc * 16);
    float4 a0 = xp[0], a1 = xp[1], a2 = xp[2], a3 = xp[3];
    float ev[16] = {a0.x, a0.y, a0.z, a0.w, a1.x, a1.y, a1.z, a1.w,
                    a2.x, a2.y, a2.z, a2.w, a3.x, a3.y, a3.z, a3.w};
#pragma unroll
    for (int k = 0; k < 16; ++k) {
      const float* wr = W + (kc * 16 + k) * HID;  // wave-uniform -> s_load
      float ek = ev[k];
#pragma unroll
      for (int c = 0; c < HID; ++c) z[c] = fmaf(ek, wr[c], z[c]);
    }
  }
  float* yr = Y + (long)r * HID;
#pragma unroll
  for (int c = 0; c < HID; c += 4) {
    float4 v = {z[c], z[c + 1], z[c + 2], z[c + 3]};
    *(float4*)(yr + c) = v;
  }
}

// ---------------- CSR aggregation (fused self-loop + bias + act) ----------------
// one wave per node; lane = channel
__global__ __launch_bounds__(256) void k_agg_csr(
    const float* __restrict__ H, const float* __restrict__ dis,
    const int* __restrict__ rowoff, const int* __restrict__ csr_src,
    const float* __restrict__ b, float* __restrict__ A, int n, int E, int relu) {
  int node = blockIdx.x * 4 + (threadIdx.x >> 6);
  if (node >= n) return;
  int c = threadIdx.x & 63;
  float dd = dis[node];
  float z = H[(long)node * HID + c] * dd * dd;  // self-loop term
  int i = rowoff[node];
  int end = (node == n - 1) ? E : rowoff[node + 1];
  for (; i < end; ++i) {
    int s = csr_src[i];              // wave-uniform address -> broadcast
    float w = dis[s] * dd;
    z = fmaf(H[(long)s * HID + c], w, z);
  }
  z += b[c];
  if (relu) z = fmaxf(z, 0.f);
  A[(long)node * HID + c] = z;
}

// ---------------- edge classifier ----------------
__device__ __forceinline__ void cls_accum(const float* __restrict__ er,
                                          const float* __restrict__ Wp,
                                          float* __restrict__ z) {
  for (int kc = 0; kc < 4; ++kc) {
    const float4* xp = (const float4*)(er + kc * 16);
    float4 a0 = xp[0], a1 = xp[1], a2 = xp[2], a3 = xp[3];
    float ev[16] = {a0.x, a0.y, a0.z, a0.w, a1.x, a1.y, a1.z, a1.w,
                    a2.x, a2.y, a2.z, a2.w, a3.x, a3.y, a3.z, a3.w};
#pragma unroll
    for (int k = 0; k < 16; ++k) {
      const float* wr = Wp + (kc * 16 + k) * HID;  // wave-uniform -> s_load
      float ek = ev[k];
#pragma unroll
      for (int c = 0; c < HID; ++c) z[c] = fmaf(ek, wr[c], z[c]);
    }
  }
}

__global__ __launch_bounds__(256) void k_classifier(
    const float* __restrict__ H, const int* __restrict__ src,
    const int* __restrict__ dst, const float* __restrict__ Wc1,
    const float* __restrict__ bc1, const float* __restrict__ Wc2,
    const float* __restrict__ bc2, float* __restrict__ out, int E) {
  int e = blockIdx.x * blockDim.x + threadIdx.x;
  if (e >= E) return;
  float z[HID];
#pragma unroll
  for (int c = 0; c < HID; ++c) z[c] = bc1[c];
  int s = src[e];
  int d = dst[e];
  cls_accum(H + (long)s * HID, Wc1, z);
  cls_accum(H + (long)d * HID, Wc1 + 64 * HID, z);
  float o0 = bc2[0], o1 = bc2[1];
#pragma unroll
  for (int c = 0; c < HID; ++c) {
    float zc = fmaxf(z[c], 0.f);
    o0 = fmaf(zc, Wc2[c * 2 + 0], o0);
    o1 = fmaf(zc, Wc2[c * 2 + 1], o1);
  }
  out[(long)e * 2 + 0] = o0;
  out[(long)e * 2 + 1] = o1;
}

// ---------------- launch ----------------
extern "C" void kernel_launch(void* const* d_in, const int* in_sizes, int n_in,
                              void* d_out, int out_size, void* d_ws, size_t ws_size,
                              hipStream_t stream) {
  const float* x   = (const float*)d_in[0];
  const int*   ei  = (const int*)d_in[1];
  const float* W1  = (const float*)d_in[2];
  const float* b1  = (const float*)d_in[3];
  const float* W2  = (const float*)d_in[4];
  const float* b2  = (const float*)d_in[5];
  const float* Wc1 = (const float*)d_in[6];
  const float* bc1 = (const float*)d_in[7];
  const float* Wc2 = (const float*)d_in[8];
  const float* bc2 = (const float*)d_in[9];

  const int N = in_sizes[0] / 128;
  const int E = in_sizes[1] / 2;
  const int* src = ei;
  const int* dst = ei + E;

  // workspace layout
  float* dis  = (float*)d_ws;          // N
  float* bufA = dis + N;               // N*64
  float* bufB = bufA + (long)N * HID;  // N*64
  int* degi     = (int*)(bufB + (long)N * HID);  // N
  int* scanout  = degi + N;                      // N
  int* rowoff   = scanout + N;                   // N
  int* cursor   = rowoff + N;                    // N
  int* blocksums= cursor + N;                    // 128
  int* csr_src  = blocksums + 128;               // E

  const int B = 256;
  int gN = (N + B - 1) / B;
  int gE = (E + B - 1) / B;
  int nb = (N + 1023) / 1024;  // scan blocks (98 for N=100000, <=128 required)

  // ---- CSR build (once, shared by both layers) ----
  k_zero_int<<<gN, B, 0, stream>>>(degi, N);
  k_count_deg<<<gE, B, 0, stream>>>(dst, degi, E);
  k_rsqrt_deg<<<gN, B, 0, stream>>>(degi, dis, N);
  k_scan1<<<nb, B, 0, stream>>>(degi, scanout, blocksums, N);
  k_scan2<<<1, 128, 0, stream>>>(blocksums, nb);
  k_scan3<<<gN, B, 0, stream>>>(scanout, blocksums, rowoff, cursor, N);
  k_scatter<<<gE, B, 0, stream>>>(src, dst, cursor, csr_src, E);

  int gAgg = (N + 3) / 4;  // 4 nodes (waves) per 256-block

  // ---- layer 1: h1 = relu(agg(x@W1) + b1) ----
  k_node_linear<128><<<gN, B, 0, stream>>>(x, W1, bufA, N);
  k_agg_csr<<<gAgg, B, 0, stream>>>(bufA, dis, rowoff, csr_src, b1, bufB, N, E, 1);

  // ---- layer 2: h2 = agg(h1@W2) + b2 ----
  k_node_linear<64><<<gN, B, 0, stream>>>(bufB, W2, bufA, N);
  k_agg_csr<<<gAgg, B, 0, stream>>>(bufA, dis, rowoff, csr_src, b2, bufB, N, E, 0);

  // ---- edge classifier ----
  k_classifier<<<gE, B, 0, stream>>>(bufB, src, dst, Wc1, bc1, Wc2, bc2,
                                     (float*)d_out, E);
}

// Round 3
// 747.479 us; speedup vs baseline: 1.7014x; 1.2713x over previous
//
#include <hip/hip_runtime.h>
#include <hip/hip_fp16.h>

#define HID 64

typedef _Float16 half8 __attribute__((ext_vector_type(8)));
typedef float f32x4 __attribute__((ext_vector_type(4)));

// ---------------- utility ----------------
__global__ void k_zero_int(int* p, int n) {
  int i = blockIdx.x * blockDim.x + threadIdx.x;
  if (i < n) p[i] = 0;
}

__global__ void k_count_deg(const int* __restrict__ dst, int* deg, int E) {
  int e = blockIdx.x * blockDim.x + threadIdx.x;
  if (e < E) atomicAdd(&deg[dst[e]], 1);
}

__global__ void k_rsqrt_deg(const int* __restrict__ deg, float* dis, int n) {
  int i = blockIdx.x * blockDim.x + threadIdx.x;
  if (i < n) dis[i] = rsqrtf((float)deg[i] + 1.0f);
}

// ---------------- exclusive scan of deg -> rowoff ----------------
__global__ void k_scan1(const int* __restrict__ deg, int* __restrict__ scanout,
                        int* __restrict__ blocksums, int n) {
  __shared__ int sdata[256];
  int tid = threadIdx.x;
  int base = blockIdx.x * 1024 + tid * 4;
  int v0 = 0, v1 = 0, v2 = 0, v3 = 0;
  if (base + 0 < n) v0 = deg[base + 0];
  if (base + 1 < n) v1 = deg[base + 1];
  if (base + 2 < n) v2 = deg[base + 2];
  if (base + 3 < n) v3 = deg[base + 3];
  int tsum = v0 + v1 + v2 + v3;
  sdata[tid] = tsum;
  __syncthreads();
  for (int off = 1; off < 256; off <<= 1) {
    int t = (tid >= off) ? sdata[tid - off] : 0;
    __syncthreads();
    sdata[tid] += t;
    __syncthreads();
  }
  int excl = sdata[tid] - tsum;
  if (base + 0 < n) scanout[base + 0] = excl;
  if (base + 1 < n) scanout[base + 1] = excl + v0;
  if (base + 2 < n) scanout[base + 2] = excl + v0 + v1;
  if (base + 3 < n) scanout[base + 3] = excl + v0 + v1 + v2;
  if (tid == 255) blocksums[blockIdx.x] = sdata[255];
}

__global__ void k_scan2(int* blocksums, int nb) {
  __shared__ int s[128];
  int tid = threadIdx.x;
  int v = (tid < nb) ? blocksums[tid] : 0;
  s[tid] = v;
  __syncthreads();
  for (int off = 1; off < 128; off <<= 1) {
    int t = (tid >= off) ? s[tid - off] : 0;
    __syncthreads();
    s[tid] += t;
    __syncthreads();
  }
  if (tid < nb) blocksums[tid] = s[tid] - v;
}

__global__ void k_scan3(const int* __restrict__ scanout,
                        const int* __restrict__ blocksums, int* __restrict__ rowoff,
                        int* __restrict__ cursor, int n) {
  int i = blockIdx.x * blockDim.x + threadIdx.x;
  if (i < n) {
    int v = scanout[i] + blocksums[i >> 10];
    rowoff[i] = v;
    cursor[i] = v;
  }
}

__global__ void k_scatter(const int* __restrict__ src, const int* __restrict__ dst,
                          int* __restrict__ cursor, int* __restrict__ csr_src, int E) {
  int e = blockIdx.x * blockDim.x + threadIdx.x;
  if (e >= E) return;
  int d = dst[e];
  int pos = atomicAdd(&cursor[d], 1);
  csr_src[pos] = src[e];
}

// ---------------- pack Wc1 into f16 MFMA B-fragment order ----------------
// frag f = kc*4+nb; lane L; j in 0..7:  B[k = 32*kc + (L>>4)*8 + j][n = (L&15)+16*nb]
__global__ void k_pack_wc1(const float* __restrict__ W, __half* __restrict__ pack) {
  int t = blockIdx.x * blockDim.x + threadIdx.x;  // one thread per (frag, lane)
  if (t >= 16 * 64) return;
  int f = t >> 6, L = t & 63;
  int kc = f >> 2, nb = f & 3;
  int kbase = 32 * kc + ((L >> 4) << 3);
  int n = (L & 15) + 16 * nb;
  for (int j = 0; j < 8; ++j)
    pack[(t << 3) + j] = __float2half(W[(kbase + j) * HID + n]);
}

// ---------------- node linear (fp32 in, f16 out): Y = X[n,128] @ W ----------------
__global__ __launch_bounds__(256) void k_lin_f32in(const float* __restrict__ X,
                                                   const float* __restrict__ W,
                                                   __half* __restrict__ Y, int n) {
  int r = blockIdx.x * blockDim.x + threadIdx.x;
  if (r >= n) return;
  float z[HID];
#pragma unroll
  for (int c = 0; c < HID; ++c) z[c] = 0.f;
  const float* xr = X + (long)r * 128;
  for (int kc = 0; kc < 8; ++kc) {
    const float4* xp = (const float4*)(xr + kc * 16);
    float4 a0 = xp[0], a1 = xp[1], a2 = xp[2], a3 = xp[3];
    float ev[16] = {a0.x, a0.y, a0.z, a0.w, a1.x, a1.y, a1.z, a1.w,
                    a2.x, a2.y, a2.z, a2.w, a3.x, a3.y, a3.z, a3.w};
#pragma unroll
    for (int k = 0; k < 16; ++k) {
      const float* wr = W + (kc * 16 + k) * HID;  // wave-uniform -> s_load
      float ek = ev[k];
#pragma unroll
      for (int c = 0; c < HID; ++c) z[c] = fmaf(ek, wr[c], z[c]);
    }
  }
  union { __half h[8]; float4 f; } u;
  float4* yr = (float4*)(Y + (long)r * HID);
#pragma unroll
  for (int g = 0; g < 8; ++g) {
#pragma unroll
    for (int j = 0; j < 8; ++j) u.h[j] = __float2half(z[g * 8 + j]);
    yr[g] = u.f;
  }
}

// ---------------- node linear (f16 in, f16 out): Y = X[n,64] @ W ----------------
__global__ __launch_bounds__(256) void k_lin_f16in(const __half* __restrict__ X,
                                                   const float* __restrict__ W,
                                                   __half* __restrict__ Y, int n) {
  int r = blockIdx.x * blockDim.x + threadIdx.x;
  if (r >= n) return;
  float z[HID];
#pragma unroll
  for (int c = 0; c < HID; ++c) z[c] = 0.f;
  const half8* xr = (const half8*)(X + (long)r * HID);
  for (int kc = 0; kc < 4; ++kc) {
    half8 a0 = xr[kc * 2], a1 = xr[kc * 2 + 1];
    float ev[16];
#pragma unroll
    for (int j = 0; j < 8; ++j) { ev[j] = (float)a0[j]; ev[8 + j] = (float)a1[j]; }
#pragma unroll
    for (int k = 0; k < 16; ++k) {
      const float* wr = W + (kc * 16 + k) * HID;  // wave-uniform -> s_load
      float ek = ev[k];
#pragma unroll
      for (int c = 0; c < HID; ++c) z[c] = fmaf(ek, wr[c], z[c]);
    }
  }
  union { __half h[8]; float4 f; } u;
  float4* yr = (float4*)(Y + (long)r * HID);
#pragma unroll
  for (int g = 0; g < 8; ++g) {
#pragma unroll
    for (int j = 0; j < 8; ++j) u.h[j] = __float2half(z[g * 8 + j]);
    yr[g] = u.f;
  }
}

// ---------------- CSR aggregation (f16 rows, fp32 accum, fused bias/act) ----------
__global__ __launch_bounds__(256) void k_agg_csr(
    const __half* __restrict__ Hf, const float* __restrict__ dis,
    const int* __restrict__ rowoff, const int* __restrict__ csr_src,
    const float* __restrict__ b, __half* __restrict__ A, int n, int E, int relu) {
  int node = blockIdx.x * 4 + (threadIdx.x >> 6);
  if (node >= n) return;
  int c = threadIdx.x & 63;
  float dd = dis[node];
  float z = __half2float(Hf[(long)node * HID + c]) * dd * dd;  // self-loop
  int i = rowoff[node];
  int end = (node == n - 1) ? E : rowoff[node + 1];
  for (; i < end; ++i) {
    int s = csr_src[i];
    float w = dis[s] * dd;
    z = fmaf(__half2float(Hf[(long)s * HID + c]), w, z);
  }
  z += b[c];
  if (relu) z = fmaxf(z, 0.f);
  A[(long)node * HID + c] = __float2half(z);
}

// ---------------- edge classifier via f16 MFMA ----------------
__global__ __launch_bounds__(256) void k_classifier_mfma(
    const __half* __restrict__ Hf, const int* __restrict__ src,
    const int* __restrict__ dst, const __half* __restrict__ pack,
    const float* __restrict__ bc1, const float* __restrict__ Wc2,
    const float* __restrict__ bc2, float* __restrict__ out, int E, int ntiles,
    int nwaves) {
  int wid = blockIdx.x * 4 + (threadIdx.x >> 6);
  int L = threadIdx.x & 63;
  int m16 = L & 15, quad = L >> 4;

  // B fragments (Wc1), persistent in VGPRs
  half8 Bf[16];
  const half8* packv = (const half8*)pack;
#pragma unroll
  for (int f = 0; f < 16; ++f) Bf[f] = packv[f * 64 + L];

  // epilogue constants: this lane's channels n = m16 + 16*nb
  float bc1v[4], w20[4], w21[4];
#pragma unroll
  for (int nb = 0; nb < 4; ++nb) {
    int n = m16 + 16 * nb;
    bc1v[nb] = bc1[n];
    w20[nb] = Wc2[2 * n];
    w21[nb] = Wc2[2 * n + 1];
  }
  float ob0 = bc2[0], ob1 = bc2[1];

  const half8* Hv = (const half8*)Hf;  // 8 half8 chunks per 64-ch row
  for (int t = wid; t < ntiles; t += nwaves) {
    int e = t * 16 + m16;
    int ec = min(e, E - 1);
    int s = src[ec], d = dst[ec];
    half8 A0 = Hv[(long)s * 8 + quad];      // k 0..31 of src row
    half8 A1 = Hv[(long)s * 8 + 4 + quad];  // k 32..63
    half8 A2 = Hv[(long)d * 8 + quad];      // k 64..95 (dst row)
    half8 A3 = Hv[(long)d * 8 + 4 + quad];  // k 96..127
    f32x4 acc[4] = {{0.f, 0.f, 0.f, 0.f},
                    {0.f, 0.f, 0.f, 0.f},
                    {0.f, 0.f, 0.f, 0.f},
                    {0.f, 0.f, 0.f, 0.f}};
#pragma unroll
    for (int nb = 0; nb < 4; ++nb) {
      acc[nb] = __builtin_amdgcn_mfma_f32_16x16x32_f16(A0, Bf[0 * 4 + nb], acc[nb], 0, 0, 0);
      acc[nb] = __builtin_amdgcn_mfma_f32_16x16x32_f16(A1, Bf[1 * 4 + nb], acc[nb], 0, 0, 0);
      acc[nb] = __builtin_amdgcn_mfma_f32_16x16x32_f16(A2, Bf[2 * 4 + nb], acc[nb], 0, 0, 0);
      acc[nb] = __builtin_amdgcn_mfma_f32_16x16x32_f16(A3, Bf[3 * 4 + nb], acc[nb], 0, 0, 0);
    }
    // epilogue: lane holds rows m = quad*4 + r, cols n = m16 + 16*nb
    float o0[4] = {0.f, 0.f, 0.f, 0.f}, o1[4] = {0.f, 0.f, 0.f, 0.f};
#pragma unroll
    for (int nb = 0; nb < 4; ++nb) {
#pragma unroll
      for (int r = 0; r < 4; ++r) {
        float v = fmaxf(acc[nb][r] + bc1v[nb], 0.f);
        o0[r] = fmaf(v, w20[nb], o0[r]);
        o1[r] = fmaf(v, w21[nb], o1[r]);
      }
    }
#pragma unroll
    for (int mask = 1; mask < 16; mask <<= 1) {
#pragma unroll
      for (int r = 0; r < 4; ++r) {
        o0[r] += __shfl_xor(o0[r], mask, 64);
        o1[r] += __shfl_xor(o1[r], mask, 64);
      }
    }
    if (m16 < 4) {
      int ee = t * 16 + quad * 4 + m16;
      if (ee < E) {
        float2 o = {o0[m16] + ob0, o1[m16] + ob1};
        *(float2*)(out + 2 * (long)ee) = o;
      }
    }
  }
}

// ---------------- launch ----------------
extern "C" void kernel_launch(void* const* d_in, const int* in_sizes, int n_in,
                              void* d_out, int out_size, void* d_ws, size_t ws_size,
                              hipStream_t stream) {
  const float* x   = (const float*)d_in[0];
  const int*   ei  = (const int*)d_in[1];
  const float* W1  = (const float*)d_in[2];
  const float* b1  = (const float*)d_in[3];
  const float* W2  = (const float*)d_in[4];
  const float* b2  = (const float*)d_in[5];
  const float* Wc1 = (const float*)d_in[6];
  const float* bc1 = (const float*)d_in[7];
  const float* Wc2 = (const float*)d_in[8];
  const float* bc2 = (const float*)d_in[9];

  const int N = in_sizes[0] / 128;
  const int E = in_sizes[1] / 2;
  const int* src = ei;
  const int* dst = ei + E;

  // workspace layout (16B-aligned segments)
  float* dis    = (float*)d_ws;                    // N f32
  __half* pack  = (__half*)(dis + N);              // 8192 f16 (Wc1 frags)
  __half* y     = pack + 8192;                     // N*64 f16 (linear out)
  __half* h     = y + (long)N * HID;               // N*64 f16 (agg out)
  int* degi     = (int*)(h + (long)N * HID);       // N
  int* scanout  = degi + N;                        // N
  int* rowoff   = scanout + N;                     // N
  int* cursor   = rowoff + N;                      // N
  int* blocksums= cursor + N;                      // 128
  int* csr_src  = blocksums + 128;                 // E

  const int B = 256;
  int gN = (N + B - 1) / B;
  int gE = (E + B - 1) / B;
  int nb = (N + 1023) / 1024;

  // ---- CSR build (once, shared by both layers) ----
  k_zero_int<<<gN, B, 0, stream>>>(degi, N);
  k_count_deg<<<gE, B, 0, stream>>>(dst, degi, E);
  k_rsqrt_deg<<<gN, B, 0, stream>>>(degi, dis, N);
  k_scan1<<<nb, B, 0, stream>>>(degi, scanout, blocksums, N);
  k_scan2<<<1, 128, 0, stream>>>(blocksums, nb);
  k_scan3<<<gN, B, 0, stream>>>(scanout, blocksums, rowoff, cursor, N);
  k_scatter<<<gE, B, 0, stream>>>(src, dst, cursor, csr_src, E);
  k_pack_wc1<<<4, B, 0, stream>>>(Wc1, pack);

  int gAgg = (N + 3) / 4;

  // ---- layer 1 ----
  k_lin_f32in<<<gN, B, 0, stream>>>(x, W1, y, N);
  k_agg_csr<<<gAgg, B, 0, stream>>>(y, dis, rowoff, csr_src, b1, h, N, E, 1);

  // ---- layer 2 ----
  k_lin_f16in<<<gN, B, 0, stream>>>(h, W2, y, N);
  k_agg_csr<<<gAgg, B, 0, stream>>>(y, dis, rowoff, csr_src, b2, h, N, E, 0);

  // ---- edge classifier (f16 MFMA, persistent grid-stride) ----
  int ntiles = (E + 15) / 16;
  int cblocks = 2048;
  int nwaves = cblocks * 4;
  k_classifier_mfma<<<cblocks, B, 0, stream>>>(h, src, dst, pack, bc1, Wc2, bc2,
                                               (float*)d_out, E, ntiles, nwaves);
}

// Round 4
// 640.348 us; speedup vs baseline: 1.9861x; 1.1673x over previous
//
#include <hip/hip_runtime.h>
#include <hip/hip_fp16.h>

#define HID 64

typedef _Float16 half8 __attribute__((ext_vector_type(8)));
typedef float f32x4 __attribute__((ext_vector_type(4)));

// ---------------- utility ----------------
__global__ void k_zero_int(int* p, int n) {
  int i = blockIdx.x * blockDim.x + threadIdx.x;
  if (i < n) p[i] = 0;
}

__global__ void k_count_deg(const int* __restrict__ dst, int* deg, int E) {
  int e = blockIdx.x * blockDim.x + threadIdx.x;
  if (e < E) atomicAdd(&deg[dst[e]], 1);
}

// ---------------- exclusive scan of deg -> rowoff (+ fused dis=rsqrt(deg+1)) ----
__global__ void k_scan1(const int* __restrict__ deg, int* __restrict__ scanout,
                        int* __restrict__ blocksums, float* __restrict__ dis, int n) {
  __shared__ int sdata[256];
  int tid = threadIdx.x;
  int base = blockIdx.x * 1024 + tid * 4;
  int v0 = 0, v1 = 0, v2 = 0, v3 = 0;
  if (base + 0 < n) v0 = deg[base + 0];
  if (base + 1 < n) v1 = deg[base + 1];
  if (base + 2 < n) v2 = deg[base + 2];
  if (base + 3 < n) v3 = deg[base + 3];
  if (base + 0 < n) dis[base + 0] = rsqrtf((float)v0 + 1.0f);
  if (base + 1 < n) dis[base + 1] = rsqrtf((float)v1 + 1.0f);
  if (base + 2 < n) dis[base + 2] = rsqrtf((float)v2 + 1.0f);
  if (base + 3 < n) dis[base + 3] = rsqrtf((float)v3 + 1.0f);
  int tsum = v0 + v1 + v2 + v3;
  sdata[tid] = tsum;
  __syncthreads();
  for (int off = 1; off < 256; off <<= 1) {
    int t = (tid >= off) ? sdata[tid - off] : 0;
    __syncthreads();
    sdata[tid] += t;
    __syncthreads();
  }
  int excl = sdata[tid] - tsum;
  if (base + 0 < n) scanout[base + 0] = excl;
  if (base + 1 < n) scanout[base + 1] = excl + v0;
  if (base + 2 < n) scanout[base + 2] = excl + v0 + v1;
  if (base + 3 < n) scanout[base + 3] = excl + v0 + v1 + v2;
  if (tid == 255) blocksums[blockIdx.x] = sdata[255];
}

__global__ void k_scan2(int* blocksums, int nb) {
  __shared__ int s[128];
  int tid = threadIdx.x;
  int v = (tid < nb) ? blocksums[tid] : 0;
  s[tid] = v;
  __syncthreads();
  for (int off = 1; off < 128; off <<= 1) {
    int t = (tid >= off) ? s[tid - off] : 0;
    __syncthreads();
    s[tid] += t;
    __syncthreads();
  }
  if (tid < nb) blocksums[tid] = s[tid] - v;
}

__global__ void k_scan3(const int* __restrict__ scanout,
                        const int* __restrict__ blocksums, int* __restrict__ rowoff,
                        int* __restrict__ cursor, int n) {
  int i = blockIdx.x * blockDim.x + threadIdx.x;
  if (i < n) {
    int v = scanout[i] + blocksums[i >> 10];
    rowoff[i] = v;
    cursor[i] = v;
  }
}

__global__ void k_scatter(const int* __restrict__ src, const int* __restrict__ dst,
                          int* __restrict__ cursor, int* __restrict__ csr_src, int E) {
  int e = blockIdx.x * blockDim.x + threadIdx.x;
  if (e >= E) return;
  int d = dst[e];
  int pos = atomicAdd(&cursor[d], 1);
  csr_src[pos] = src[e];
}

// ---------------- pack Wc1 into f16 MFMA B-fragment order ----------------
__global__ void k_pack_wc1(const float* __restrict__ W, __half* __restrict__ pack) {
  int t = blockIdx.x * blockDim.x + threadIdx.x;
  if (t >= 16 * 64) return;
  int f = t >> 6, L = t & 63;
  int kc = f >> 2, nb = f & 3;
  int kbase = 32 * kc + ((L >> 4) << 3);
  int n = (L & 15) + 16 * nb;
  for (int j = 0; j < 8; ++j)
    pack[(t << 3) + j] = __float2half(W[(kbase + j) * HID + n]);
}

// ---------------- node linear (fp32 in, f16 out) ----------------
__global__ __launch_bounds__(256) void k_lin_f32in(const float* __restrict__ X,
                                                   const float* __restrict__ W,
                                                   __half* __restrict__ Y, int n) {
  int r = blockIdx.x * blockDim.x + threadIdx.x;
  if (r >= n) return;
  float z[HID];
#pragma unroll
  for (int c = 0; c < HID; ++c) z[c] = 0.f;
  const float* xr = X + (long)r * 128;
  for (int kc = 0; kc < 8; ++kc) {
    const float4* xp = (const float4*)(xr + kc * 16);
    float4 a0 = xp[0], a1 = xp[1], a2 = xp[2], a3 = xp[3];
    float ev[16] = {a0.x, a0.y, a0.z, a0.w, a1.x, a1.y, a1.z, a1.w,
                    a2.x, a2.y, a2.z, a2.w, a3.x, a3.y, a3.z, a3.w};
#pragma unroll
    for (int k = 0; k < 16; ++k) {
      const float* wr = W + (kc * 16 + k) * HID;
      float ek = ev[k];
#pragma unroll
      for (int c = 0; c < HID; ++c) z[c] = fmaf(ek, wr[c], z[c]);
    }
  }
  union { __half h[8]; float4 f; } u;
  float4* yr = (float4*)(Y + (long)r * HID);
#pragma unroll
  for (int g = 0; g < 8; ++g) {
#pragma unroll
    for (int j = 0; j < 8; ++j) u.h[j] = __float2half(z[g * 8 + j]);
    yr[g] = u.f;
  }
}

// ---------------- node linear (f16 in, f16 out) ----------------
__global__ __launch_bounds__(256) void k_lin_f16in(const __half* __restrict__ X,
                                                   const float* __restrict__ W,
                                                   __half* __restrict__ Y, int n) {
  int r = blockIdx.x * blockDim.x + threadIdx.x;
  if (r >= n) return;
  float z[HID];
#pragma unroll
  for (int c = 0; c < HID; ++c) z[c] = 0.f;
  const half8* xr = (const half8*)(X + (long)r * HID);
  for (int kc = 0; kc < 4; ++kc) {
    half8 a0 = xr[kc * 2], a1 = xr[kc * 2 + 1];
    float ev[16];
#pragma unroll
    for (int j = 0; j < 8; ++j) { ev[j] = (float)a0[j]; ev[8 + j] = (float)a1[j]; }
#pragma unroll
    for (int k = 0; k < 16; ++k) {
      const float* wr = W + (kc * 16 + k) * HID;
      float ek = ev[k];
#pragma unroll
      for (int c = 0; c < HID; ++c) z[c] = fmaf(ek, wr[c], z[c]);
    }
  }
  union { __half h[8]; float4 f; } u;
  float4* yr = (float4*)(Y + (long)r * HID);
#pragma unroll
  for (int g = 0; g < 8; ++g) {
#pragma unroll
    for (int j = 0; j < 8; ++j) u.h[j] = __float2half(z[g * 8 + j]);
    yr[g] = u.f;
  }
}

// ---------------- CSR aggregation, MLP-style ----------------
// one wave per node; half-wave per edge (half2 = 2 channels/lane);
// 4 slots unrolled -> 8 edges in flight per iteration.
__global__ __launch_bounds__(256) void k_agg_csr(
    const __half* __restrict__ Hf, const float* __restrict__ dis,
    const int* __restrict__ rowoff, const int* __restrict__ csr_src,
    const float* __restrict__ b, __half* __restrict__ A, int n, int E, int relu) {
  int node = blockIdx.x * 4 + (threadIdx.x >> 6);
  if (node >= n) return;
  int L = threadIdx.x & 63;
  int sub = L >> 5;   // which edge of the pair
  int cp = L & 31;    // channel pair index (channels 2cp, 2cp+1)
  const __half2* H2 = (const __half2*)Hf;
  float dd = dis[node];
  int i0 = rowoff[node];
  int end = (node == n - 1) ? E : rowoff[node + 1];

  float2 z[4];
#pragma unroll
  for (int q = 0; q < 4; ++q) { z[q].x = 0.f; z[q].y = 0.f; }
  if (sub == 0) {  // self-loop term, once
    __half2 hv = H2[(long)node * 32 + cp];
    float w = dd * dd;
    z[0].x = __low2float(hv) * w;
    z[0].y = __high2float(hv) * w;
  }

  int last = end - 1;
  for (int base = i0; base < end; base += 8) {
#pragma unroll
    for (int slot = 0; slot < 4; ++slot) {
      int idx = base + slot * 2 + sub;
      int idxc = min(idx, last);
      int s = csr_src[idxc];                    // broadcast within half-wave
      float w = (idx < end) ? dis[s] * dd : 0.f;
      __half2 hv = H2[(long)s * 32 + cp];
      z[slot].x = fmaf(__low2float(hv), w, z[slot].x);
      z[slot].y = fmaf(__high2float(hv), w, z[slot].y);
    }
  }

  float ax = (z[0].x + z[1].x) + (z[2].x + z[3].x);
  float ay = (z[0].y + z[1].y) + (z[2].y + z[3].y);
  ax += __shfl_xor(ax, 32, 64);
  ay += __shfl_xor(ay, 32, 64);
  if (sub == 0) {
    float2 bb = ((const float2*)b)[cp];
    float vx = ax + bb.x, vy = ay + bb.y;
    if (relu) { vx = fmaxf(vx, 0.f); vy = fmaxf(vy, 0.f); }
    ((__half2*)A)[(long)node * 32 + cp] = __floats2half2_rn(vx, vy);
  }
}

// ---------------- edge classifier via f16 MFMA ----------------
__global__ __launch_bounds__(256) void k_classifier_mfma(
    const __half* __restrict__ Hf, const int* __restrict__ src,
    const int* __restrict__ dst, const __half* __restrict__ pack,
    const float* __restrict__ bc1, const float* __restrict__ Wc2,
    const float* __restrict__ bc2, float* __restrict__ out, int E, int ntiles,
    int nwaves) {
  int wid = blockIdx.x * 4 + (threadIdx.x >> 6);
  int L = threadIdx.x & 63;
  int m16 = L & 15, quad = L >> 4;

  half8 Bf[16];
  const half8* packv = (const half8*)pack;
#pragma unroll
  for (int f = 0; f < 16; ++f) Bf[f] = packv[f * 64 + L];

  float bc1v[4], w20[4], w21[4];
#pragma unroll
  for (int nb = 0; nb < 4; ++nb) {
    int n = m16 + 16 * nb;
    bc1v[nb] = bc1[n];
    w20[nb] = Wc2[2 * n];
    w21[nb] = Wc2[2 * n + 1];
  }
  float ob0 = bc2[0], ob1 = bc2[1];

  const half8* Hv = (const half8*)Hf;
  for (int t = wid; t < ntiles; t += nwaves) {
    int e = t * 16 + m16;
    int ec = min(e, E - 1);
    int s = src[ec], d = dst[ec];
    half8 A0 = Hv[(long)s * 8 + quad];
    half8 A1 = Hv[(long)s * 8 + 4 + quad];
    half8 A2 = Hv[(long)d * 8 + quad];
    half8 A3 = Hv[(long)d * 8 + 4 + quad];
    f32x4 acc[4] = {{0.f, 0.f, 0.f, 0.f},
                    {0.f, 0.f, 0.f, 0.f},
                    {0.f, 0.f, 0.f, 0.f},
                    {0.f, 0.f, 0.f, 0.f}};
#pragma unroll
    for (int nb = 0; nb < 4; ++nb) {
      acc[nb] = __builtin_amdgcn_mfma_f32_16x16x32_f16(A0, Bf[0 * 4 + nb], acc[nb], 0, 0, 0);
      acc[nb] = __builtin_amdgcn_mfma_f32_16x16x32_f16(A1, Bf[1 * 4 + nb], acc[nb], 0, 0, 0);
      acc[nb] = __builtin_amdgcn_mfma_f32_16x16x32_f16(A2, Bf[2 * 4 + nb], acc[nb], 0, 0, 0);
      acc[nb] = __builtin_amdgcn_mfma_f32_16x16x32_f16(A3, Bf[3 * 4 + nb], acc[nb], 0, 0, 0);
    }
    float o0[4] = {0.f, 0.f, 0.f, 0.f}, o1[4] = {0.f, 0.f, 0.f, 0.f};
#pragma unroll
    for (int nb = 0; nb < 4; ++nb) {
#pragma unroll
      for (int r = 0; r < 4; ++r) {
        float v = fmaxf(acc[nb][r] + bc1v[nb], 0.f);
        o0[r] = fmaf(v, w20[nb], o0[r]);
        o1[r] = fmaf(v, w21[nb], o1[r]);
      }
    }
#pragma unroll
    for (int mask = 1; mask < 16; mask <<= 1) {
#pragma unroll
      for (int r = 0; r < 4; ++r) {
        o0[r] += __shfl_xor(o0[r], mask, 64);
        o1[r] += __shfl_xor(o1[r], mask, 64);
      }
    }
    if (m16 < 4) {
      int ee = t * 16 + quad * 4 + m16;
      if (ee < E) {
        float2 o = {o0[m16] + ob0, o1[m16] + ob1};
        *(float2*)(out + 2 * (long)ee) = o;
      }
    }
  }
}

// ---------------- launch ----------------
extern "C" void kernel_launch(void* const* d_in, const int* in_sizes, int n_in,
                              void* d_out, int out_size, void* d_ws, size_t ws_size,
                              hipStream_t stream) {
  const float* x   = (const float*)d_in[0];
  const int*   ei  = (const int*)d_in[1];
  const float* W1  = (const float*)d_in[2];
  const float* b1  = (const float*)d_in[3];
  const float* W2  = (const float*)d_in[4];
  const float* b2  = (const float*)d_in[5];
  const float* Wc1 = (const float*)d_in[6];
  const float* bc1 = (const float*)d_in[7];
  const float* Wc2 = (const float*)d_in[8];
  const float* bc2 = (const float*)d_in[9];

  const int N = in_sizes[0] / 128;
  const int E = in_sizes[1] / 2;
  const int* src = ei;
  const int* dst = ei + E;

  // workspace layout
  float* dis    = (float*)d_ws;                    // N f32
  __half* pack  = (__half*)(dis + N);              // 8192 f16
  __half* y     = pack + 8192;                     // N*64 f16
  __half* h     = y + (long)N * HID;               // N*64 f16
  int* degi     = (int*)(h + (long)N * HID);       // N
  int* scanout  = degi + N;                        // N
  int* rowoff   = scanout + N;                     // N
  int* cursor   = rowoff + N;                      // N
  int* blocksums= cursor + N;                      // 128
  int* csr_src  = blocksums + 128;                 // E

  const int B = 256;
  int gN = (N + B - 1) / B;
  int gE = (E + B - 1) / B;
  int nb = (N + 1023) / 1024;

  // ---- CSR build ----
  k_zero_int<<<gN, B, 0, stream>>>(degi, N);
  k_count_deg<<<gE, B, 0, stream>>>(dst, degi, E);
  k_scan1<<<nb, B, 0, stream>>>(degi, scanout, blocksums, dis, N);
  k_scan2<<<1, 128, 0, stream>>>(blocksums, nb);
  k_scan3<<<gN, B, 0, stream>>>(scanout, blocksums, rowoff, cursor, N);
  k_scatter<<<gE, B, 0, stream>>>(src, dst, cursor, csr_src, E);
  k_pack_wc1<<<4, B, 0, stream>>>(Wc1, pack);

  int gAgg = (N + 3) / 4;

  // ---- layer 1 ----
  k_lin_f32in<<<gN, B, 0, stream>>>(x, W1, y, N);
  k_agg_csr<<<gAgg, B, 0, stream>>>(y, dis, rowoff, csr_src, b1, h, N, E, 1);

  // ---- layer 2 ----
  k_lin_f16in<<<gN, B, 0, stream>>>(h, W2, y, N);
  k_agg_csr<<<gAgg, B, 0, stream>>>(y, dis, rowoff, csr_src, b2, h, N, E, 0);

  // ---- edge classifier ----
  int ntiles = (E + 15) / 16;
  int cblocks = 2048;
  int nwaves = cblocks * 4;
  k_classifier_mfma<<<cblocks, B, 0, stream>>>(h, src, dst, pack, bc1, Wc2, bc2,
                                               (float*)d_out, E, ntiles, nwaves);
}

// Round 5
// 556.789 us; speedup vs baseline: 2.2841x; 1.1501x over previous
//
#include <hip/hip_runtime.h>
#include <hip/hip_fp16.h>

#define HID 64

typedef _Float16 half8 __attribute__((ext_vector_type(8)));
typedef float f32x4 __attribute__((ext_vector_type(4)));

// ---------------- degree count + per-edge rank (atomic return value) ----------
__global__ void k_count_rank(const int* __restrict__ dst, int* __restrict__ deg,
                             int* __restrict__ rank, int E) {
  int e = blockIdx.x * blockDim.x + threadIdx.x;
  if (e < E) rank[e] = atomicAdd(&deg[dst[e]], 1);
}

// ---------------- exclusive scan of deg -> rowoff (+ fused dis=rsqrt(deg+1)) ----
__global__ void k_scan1(const int* __restrict__ deg, int* __restrict__ scanout,
                        int* __restrict__ blocksums, float* __restrict__ dis, int n) {
  __shared__ int sdata[256];
  int tid = threadIdx.x;
  int base = blockIdx.x * 1024 + tid * 4;
  int v0 = 0, v1 = 0, v2 = 0, v3 = 0;
  if (base + 0 < n) v0 = deg[base + 0];
  if (base + 1 < n) v1 = deg[base + 1];
  if (base + 2 < n) v2 = deg[base + 2];
  if (base + 3 < n) v3 = deg[base + 3];
  if (base + 0 < n) dis[base + 0] = rsqrtf((float)v0 + 1.0f);
  if (base + 1 < n) dis[base + 1] = rsqrtf((float)v1 + 1.0f);
  if (base + 2 < n) dis[base + 2] = rsqrtf((float)v2 + 1.0f);
  if (base + 3 < n) dis[base + 3] = rsqrtf((float)v3 + 1.0f);
  int tsum = v0 + v1 + v2 + v3;
  sdata[tid] = tsum;
  __syncthreads();
  for (int off = 1; off < 256; off <<= 1) {
    int t = (tid >= off) ? sdata[tid - off] : 0;
    __syncthreads();
    sdata[tid] += t;
    __syncthreads();
  }
  int excl = sdata[tid] - tsum;
  if (base + 0 < n) scanout[base + 0] = excl;
  if (base + 1 < n) scanout[base + 1] = excl + v0;
  if (base + 2 < n) scanout[base + 2] = excl + v0 + v1;
  if (base + 3 < n) scanout[base + 3] = excl + v0 + v1 + v2;
  if (tid == 255) blocksums[blockIdx.x] = sdata[255];
}

__global__ void k_scan2(int* blocksums, int nb) {
  __shared__ int s[128];
  int tid = threadIdx.x;
  int v = (tid < nb) ? blocksums[tid] : 0;
  s[tid] = v;
  __syncthreads();
  for (int off = 1; off < 128; off <<= 1) {
    int t = (tid >= off) ? s[tid - off] : 0;
    __syncthreads();
    s[tid] += t;
    __syncthreads();
  }
  if (tid < nb) blocksums[tid] = s[tid] - v;
}

__global__ void k_scan3(const int* __restrict__ scanout,
                        const int* __restrict__ blocksums, int* __restrict__ rowoff,
                        int n) {
  int i = blockIdx.x * blockDim.x + threadIdx.x;
  if (i < n) rowoff[i] = scanout[i] + blocksums[i >> 10];
}

// ---------------- deterministic scatter (no atomics, fire-and-forget store) ----
__global__ void k_scatter_det(const int* __restrict__ src, const int* __restrict__ dst,
                              const int* __restrict__ rowoff,
                              const int* __restrict__ rank,
                              int* __restrict__ csr_src, int E) {
  int e = blockIdx.x * blockDim.x + threadIdx.x;
  if (e >= E) return;
  int pos = rowoff[dst[e]] + rank[e];
  csr_src[pos] = src[e];
}

// ---------------- pack Wc1 into f16 MFMA B-fragment order ----------------
__global__ void k_pack_wc1(const float* __restrict__ W, __half* __restrict__ pack) {
  int t = blockIdx.x * blockDim.x + threadIdx.x;
  if (t >= 16 * 64) return;
  int f = t >> 6, L = t & 63;
  int kc = f >> 2, nb = f & 3;
  int kbase = 32 * kc + ((L >> 4) << 3);
  int n = (L & 15) + 16 * nb;
  for (int j = 0; j < 8; ++j)
    pack[(t << 3) + j] = __float2half(W[(kbase + j) * HID + n]);
}

// ---------------- node linear (fp32 in, f16 out) ----------------
__global__ __launch_bounds__(256) void k_lin_f32in(const float* __restrict__ X,
                                                   const float* __restrict__ W,
                                                   __half* __restrict__ Y, int n) {
  int r = blockIdx.x * blockDim.x + threadIdx.x;
  if (r >= n) return;
  float z[HID];
#pragma unroll
  for (int c = 0; c < HID; ++c) z[c] = 0.f;
  const float* xr = X + (long)r * 128;
  for (int kc = 0; kc < 8; ++kc) {
    const float4* xp = (const float4*)(xr + kc * 16);
    float4 a0 = xp[0], a1 = xp[1], a2 = xp[2], a3 = xp[3];
    float ev[16] = {a0.x, a0.y, a0.z, a0.w, a1.x, a1.y, a1.z, a1.w,
                    a2.x, a2.y, a2.z, a2.w, a3.x, a3.y, a3.z, a3.w};
#pragma unroll
    for (int k = 0; k < 16; ++k) {
      const float* wr = W + (kc * 16 + k) * HID;
      float ek = ev[k];
#pragma unroll
      for (int c = 0; c < HID; ++c) z[c] = fmaf(ek, wr[c], z[c]);
    }
  }
  union { __half h[8]; float4 f; } u;
  float4* yr = (float4*)(Y + (long)r * HID);
#pragma unroll
  for (int g = 0; g < 8; ++g) {
#pragma unroll
    for (int j = 0; j < 8; ++j) u.h[j] = __float2half(z[g * 8 + j]);
    yr[g] = u.f;
  }
}

// ---------------- node linear (f16 in, f16 out) ----------------
__global__ __launch_bounds__(256) void k_lin_f16in(const __half* __restrict__ X,
                                                   const float* __restrict__ W,
                                                   __half* __restrict__ Y, int n) {
  int r = blockIdx.x * blockDim.x + threadIdx.x;
  if (r >= n) return;
  float z[HID];
#pragma unroll
  for (int c = 0; c < HID; ++c) z[c] = 0.f;
  const half8* xr = (const half8*)(X + (long)r * HID);
  for (int kc = 0; kc < 4; ++kc) {
    half8 a0 = xr[kc * 2], a1 = xr[kc * 2 + 1];
    float ev[16];
#pragma unroll
    for (int j = 0; j < 8; ++j) { ev[j] = (float)a0[j]; ev[8 + j] = (float)a1[j]; }
#pragma unroll
    for (int k = 0; k < 16; ++k) {
      const float* wr = W + (kc * 16 + k) * HID;
      float ek = ev[k];
#pragma unroll
      for (int c = 0; c < HID; ++c) z[c] = fmaf(ek, wr[c], z[c]);
    }
  }
  union { __half h[8]; float4 f; } u;
  float4* yr = (float4*)(Y + (long)r * HID);
#pragma unroll
  for (int g = 0; g < 8; ++g) {
#pragma unroll
    for (int j = 0; j < 8; ++j) u.h[j] = __float2half(z[g * 8 + j]);
    yr[g] = u.f;
  }
}

// ---------------- CSR aggregation, MLP-style ----------------
// one wave per node; half-wave per edge (half2 = 2 channels/lane);
// 4 slots unrolled -> 8 edges in flight per iteration.
__global__ __launch_bounds__(256) void k_agg_csr(
    const __half* __restrict__ Hf, const float* __restrict__ dis,
    const int* __restrict__ rowoff, const int* __restrict__ csr_src,
    const float* __restrict__ b, __half* __restrict__ A, int n, int E, int relu) {
  int node = blockIdx.x * 4 + (threadIdx.x >> 6);
  if (node >= n) return;
  int L = threadIdx.x & 63;
  int sub = L >> 5;
  int cp = L & 31;
  const __half2* H2 = (const __half2*)Hf;
  float dd = dis[node];
  int i0 = rowoff[node];
  int end = (node == n - 1) ? E : rowoff[node + 1];

  float2 z[4];
#pragma unroll
  for (int q = 0; q < 4; ++q) { z[q].x = 0.f; z[q].y = 0.f; }
  if (sub == 0) {
    __half2 hv = H2[(long)node * 32 + cp];
    float w = dd * dd;
    z[0].x = __low2float(hv) * w;
    z[0].y = __high2float(hv) * w;
  }

  int last = end - 1;
  for (int base = i0; base < end; base += 8) {
#pragma unroll
    for (int slot = 0; slot < 4; ++slot) {
      int idx = base + slot * 2 + sub;
      int idxc = min(idx, last);
      int s = csr_src[idxc];
      float w = (idx < end) ? dis[s] * dd : 0.f;
      __half2 hv = H2[(long)s * 32 + cp];
      z[slot].x = fmaf(__low2float(hv), w, z[slot].x);
      z[slot].y = fmaf(__high2float(hv), w, z[slot].y);
    }
  }

  float ax = (z[0].x + z[1].x) + (z[2].x + z[3].x);
  float ay = (z[0].y + z[1].y) + (z[2].y + z[3].y);
  ax += __shfl_xor(ax, 32, 64);
  ay += __shfl_xor(ay, 32, 64);
  if (sub == 0) {
    float2 bb = ((const float2*)b)[cp];
    float vx = ax + bb.x, vy = ay + bb.y;
    if (relu) { vx = fmaxf(vx, 0.f); vy = fmaxf(vy, 0.f); }
    ((__half2*)A)[(long)node * 32 + cp] = __floats2half2_rn(vx, vy);
  }
}

// ---------------- edge classifier via f16 MFMA ----------------
__global__ __launch_bounds__(256) void k_classifier_mfma(
    const __half* __restrict__ Hf, const int* __restrict__ src,
    const int* __restrict__ dst, const __half* __restrict__ pack,
    const float* __restrict__ bc1, const float* __restrict__ Wc2,
    const float* __restrict__ bc2, float* __restrict__ out, int E, int ntiles,
    int nwaves) {
  int wid = blockIdx.x * 4 + (threadIdx.x >> 6);
  int L = threadIdx.x & 63;
  int m16 = L & 15, quad = L >> 4;

  half8 Bf[16];
  const half8* packv = (const half8*)pack;
#pragma unroll
  for (int f = 0; f < 16; ++f) Bf[f] = packv[f * 64 + L];

  float bc1v[4], w20[4], w21[4];
#pragma unroll
  for (int nb = 0; nb < 4; ++nb) {
    int n = m16 + 16 * nb;
    bc1v[nb] = bc1[n];
    w20[nb] = Wc2[2 * n];
    w21[nb] = Wc2[2 * n + 1];
  }
  float ob0 = bc2[0], ob1 = bc2[1];

  const half8* Hv = (const half8*)Hf;
  for (int t = wid; t < ntiles; t += nwaves) {
    int e = t * 16 + m16;
    int ec = min(e, E - 1);
    int s = src[ec], d = dst[ec];
    half8 A0 = Hv[(long)s * 8 + quad];
    half8 A1 = Hv[(long)s * 8 + 4 + quad];
    half8 A2 = Hv[(long)d * 8 + quad];
    half8 A3 = Hv[(long)d * 8 + 4 + quad];
    f32x4 acc[4] = {{0.f, 0.f, 0.f, 0.f},
                    {0.f, 0.f, 0.f, 0.f},
                    {0.f, 0.f, 0.f, 0.f},
                    {0.f, 0.f, 0.f, 0.f}};
#pragma unroll
    for (int nb = 0; nb < 4; ++nb) {
      acc[nb] = __builtin_amdgcn_mfma_f32_16x16x32_f16(A0, Bf[0 * 4 + nb], acc[nb], 0, 0, 0);
      acc[nb] = __builtin_amdgcn_mfma_f32_16x16x32_f16(A1, Bf[1 * 4 + nb], acc[nb], 0, 0, 0);
      acc[nb] = __builtin_amdgcn_mfma_f32_16x16x32_f16(A2, Bf[2 * 4 + nb], acc[nb], 0, 0, 0);
      acc[nb] = __builtin_amdgcn_mfma_f32_16x16x32_f16(A3, Bf[3 * 4 + nb], acc[nb], 0, 0, 0);
    }
    float o0[4] = {0.f, 0.f, 0.f, 0.f}, o1[4] = {0.f, 0.f, 0.f, 0.f};
#pragma unroll
    for (int nb = 0; nb < 4; ++nb) {
#pragma unroll
      for (int r = 0; r < 4; ++r) {
        float v = fmaxf(acc[nb][r] + bc1v[nb], 0.f);
        o0[r] = fmaf(v, w20[nb], o0[r]);
        o1[r] = fmaf(v, w21[nb], o1[r]);
      }
    }
#pragma unroll
    for (int mask = 1; mask < 16; mask <<= 1) {
#pragma unroll
      for (int r = 0; r < 4; ++r) {
        o0[r] += __shfl_xor(o0[r], mask, 64);
        o1[r] += __shfl_xor(o1[r], mask, 64);
      }
    }
    if (m16 < 4) {
      int ee = t * 16 + quad * 4 + m16;
      if (ee < E) {
        float2 o = {o0[m16] + ob0, o1[m16] + ob1};
        *(float2*)(out + 2 * (long)ee) = o;
      }
    }
  }
}

// ---------------- launch ----------------
extern "C" void kernel_launch(void* const* d_in, const int* in_sizes, int n_in,
                              void* d_out, int out_size, void* d_ws, size_t ws_size,
                              hipStream_t stream) {
  const float* x   = (const float*)d_in[0];
  const int*   ei  = (const int*)d_in[1];
  const float* W1  = (const float*)d_in[2];
  const float* b1  = (const float*)d_in[3];
  const float* W2  = (const float*)d_in[4];
  const float* b2  = (const float*)d_in[5];
  const float* Wc1 = (const float*)d_in[6];
  const float* bc1 = (const float*)d_in[7];
  const float* Wc2 = (const float*)d_in[8];
  const float* bc2 = (const float*)d_in[9];

  const int N = in_sizes[0] / 128;
  const int E = in_sizes[1] / 2;
  const int* src = ei;
  const int* dst = ei + E;

  // workspace layout
  float* dis    = (float*)d_ws;                    // N f32
  __half* pack  = (__half*)(dis + N);              // 8192 f16
  __half* y     = pack + 8192;                     // N*64 f16 (aliased by rank during CSR build)
  __half* h     = y + (long)N * HID;               // N*64 f16
  int* degi     = (int*)(h + (long)N * HID);       // N
  int* scanout  = degi + N;                        // N
  int* rowoff   = scanout + N;                     // N
  int* blocksums= rowoff + N;                      // 128
  int* csr_src  = blocksums + 128;                 // E
  int* rank     = (int*)y;  // E ints <= N*64 f16 bytes; dead once y is written

  const int B = 256;
  int gN = (N + B - 1) / B;
  int gE = (E + B - 1) / B;
  int nb = (N + 1023) / 1024;

  // ---- CSR build ----
  hipMemsetAsync(degi, 0, (size_t)N * sizeof(int), stream);
  k_count_rank<<<gE, B, 0, stream>>>(dst, degi, rank, E);
  k_scan1<<<nb, B, 0, stream>>>(degi, scanout, blocksums, dis, N);
  k_scan2<<<1, 128, 0, stream>>>(blocksums, nb);
  k_scan3<<<gN, B, 0, stream>>>(scanout, blocksums, rowoff, N);
  k_scatter_det<<<gE, B, 0, stream>>>(src, dst, rowoff, rank, csr_src, E);
  k_pack_wc1<<<4, B, 0, stream>>>(Wc1, pack);

  int gAgg = (N + 3) / 4;

  // ---- layer 1 ----
  k_lin_f32in<<<gN, B, 0, stream>>>(x, W1, y, N);
  k_agg_csr<<<gAgg, B, 0, stream>>>(y, dis, rowoff, csr_src, b1, h, N, E, 1);

  // ---- layer 2 ----
  k_lin_f16in<<<gN, B, 0, stream>>>(h, W2, y, N);
  k_agg_csr<<<gAgg, B, 0, stream>>>(y, dis, rowoff, csr_src, b2, h, N, E, 0);

  // ---- edge classifier ----
  int ntiles = (E + 15) / 16;
  int cblocks = 2048;
  int nwaves = cblocks * 4;
  k_classifier_mfma<<<cblocks, B, 0, stream>>>(h, src, dst, pack, bc1, Wc2, bc2,
                                               (float*)d_out, E, ntiles, nwaves);
}

// Round 6
// 494.608 us; speedup vs baseline: 2.5713x; 1.1257x over previous
//
#include <hip/hip_runtime.h>
#include <hip/hip_fp16.h>

#define HID 64

typedef _Float16 half8 __attribute__((ext_vector_type(8)));
typedef _Float16 half4 __attribute__((ext_vector_type(4)));
typedef float f32x4 __attribute__((ext_vector_type(4)));

// ---------------- degree count + per-edge rank (atomic return value) ----------
__global__ void k_count_rank(const int* __restrict__ dst, int* __restrict__ deg,
                             int* __restrict__ rank, int E) {
  int e = blockIdx.x * blockDim.x + threadIdx.x;
  if (e < E) rank[e] = atomicAdd(&deg[dst[e]], 1);
}

// ---------------- exclusive scan of deg -> rowoff (+ fused dis=rsqrt(deg+1)) ----
__global__ void k_scan1(const int* __restrict__ deg, int* __restrict__ scanout,
                        int* __restrict__ blocksums, float* __restrict__ dis, int n) {
  __shared__ int sdata[256];
  int tid = threadIdx.x;
  int base = blockIdx.x * 1024 + tid * 4;
  int v0 = 0, v1 = 0, v2 = 0, v3 = 0;
  if (base + 0 < n) v0 = deg[base + 0];
  if (base + 1 < n) v1 = deg[base + 1];
  if (base + 2 < n) v2 = deg[base + 2];
  if (base + 3 < n) v3 = deg[base + 3];
  if (base + 0 < n) dis[base + 0] = rsqrtf((float)v0 + 1.0f);
  if (base + 1 < n) dis[base + 1] = rsqrtf((float)v1 + 1.0f);
  if (base + 2 < n) dis[base + 2] = rsqrtf((float)v2 + 1.0f);
  if (base + 3 < n) dis[base + 3] = rsqrtf((float)v3 + 1.0f);
  int tsum = v0 + v1 + v2 + v3;
  sdata[tid] = tsum;
  __syncthreads();
  for (int off = 1; off < 256; off <<= 1) {
    int t = (tid >= off) ? sdata[tid - off] : 0;
    __syncthreads();
    sdata[tid] += t;
    __syncthreads();
  }
  int excl = sdata[tid] - tsum;
  if (base + 0 < n) scanout[base + 0] = excl;
  if (base + 1 < n) scanout[base + 1] = excl + v0;
  if (base + 2 < n) scanout[base + 2] = excl + v0 + v1;
  if (base + 3 < n) scanout[base + 3] = excl + v0 + v1 + v2;
  if (tid == 255) blocksums[blockIdx.x] = sdata[255];
}

__global__ void k_scan2(int* blocksums, int nb) {
  __shared__ int s[128];
  int tid = threadIdx.x;
  int v = (tid < nb) ? blocksums[tid] : 0;
  s[tid] = v;
  __syncthreads();
  for (int off = 1; off < 128; off <<= 1) {
    int t = (tid >= off) ? s[tid - off] : 0;
    __syncthreads();
    s[tid] += t;
    __syncthreads();
  }
  if (tid < nb) blocksums[tid] = s[tid] - v;
}

__global__ void k_scan3(const int* __restrict__ scanout,
                        const int* __restrict__ blocksums, int* __restrict__ rowoff,
                        int n) {
  int i = blockIdx.x * blockDim.x + threadIdx.x;
  if (i < n) rowoff[i] = scanout[i] + blocksums[i >> 10];
}

// ---------------- deterministic scatter (no atomics, fire-and-forget store) ----
__global__ void k_scatter_det(const int* __restrict__ src, const int* __restrict__ dst,
                              const int* __restrict__ rowoff,
                              const int* __restrict__ rank,
                              int* __restrict__ csr_src, int E) {
  int e = blockIdx.x * blockDim.x + threadIdx.x;
  if (e >= E) return;
  int pos = rowoff[dst[e]] + rank[e];
  csr_src[pos] = src[e];
}

// ---------------- pack Wc1 into f16 MFMA B-fragment order ----------------
__global__ void k_pack_wc1(const float* __restrict__ W, __half* __restrict__ pack) {
  int t = blockIdx.x * blockDim.x + threadIdx.x;
  if (t >= 16 * 64) return;
  int f = t >> 6, L = t & 63;
  int kc = f >> 2, nb = f & 3;
  int kbase = 32 * kc + ((L >> 4) << 3);
  int n = (L & 15) + 16 * nb;
  for (int j = 0; j < 8; ++j)
    pack[(t << 3) + j] = __float2half(W[(kbase + j) * HID + n]);
}

// ---------------- node linear (fp32 in, f16 out) ----------------
__global__ __launch_bounds__(256) void k_lin_f32in(const float* __restrict__ X,
                                                   const float* __restrict__ W,
                                                   __half* __restrict__ Y, int n) {
  int r = blockIdx.x * blockDim.x + threadIdx.x;
  if (r >= n) return;
  float z[HID];
#pragma unroll
  for (int c = 0; c < HID; ++c) z[c] = 0.f;
  const float* xr = X + (long)r * 128;
  for (int kc = 0; kc < 8; ++kc) {
    const float4* xp = (const float4*)(xr + kc * 16);
    float4 a0 = xp[0], a1 = xp[1], a2 = xp[2], a3 = xp[3];
    float ev[16] = {a0.x, a0.y, a0.z, a0.w, a1.x, a1.y, a1.z, a1.w,
                    a2.x, a2.y, a2.z, a2.w, a3.x, a3.y, a3.z, a3.w};
#pragma unroll
    for (int k = 0; k < 16; ++k) {
      const float* wr = W + (kc * 16 + k) * HID;
      float ek = ev[k];
#pragma unroll
      for (int c = 0; c < HID; ++c) z[c] = fmaf(ek, wr[c], z[c]);
    }
  }
  union { __half h[8]; float4 f; } u;
  float4* yr = (float4*)(Y + (long)r * HID);
#pragma unroll
  for (int g = 0; g < 8; ++g) {
#pragma unroll
    for (int j = 0; j < 8; ++j) u.h[j] = __float2half(z[g * 8 + j]);
    yr[g] = u.f;
  }
}

// ---------------- node linear (f16 in, f16 out) ----------------
__global__ __launch_bounds__(256) void k_lin_f16in(const __half* __restrict__ X,
                                                   const float* __restrict__ W,
                                                   __half* __restrict__ Y, int n) {
  int r = blockIdx.x * blockDim.x + threadIdx.x;
  if (r >= n) return;
  float z[HID];
#pragma unroll
  for (int c = 0; c < HID; ++c) z[c] = 0.f;
  const half8* xr = (const half8*)(X + (long)r * HID);
  for (int kc = 0; kc < 4; ++kc) {
    half8 a0 = xr[kc * 2], a1 = xr[kc * 2 + 1];
    float ev[16];
#pragma unroll
    for (int j = 0; j < 8; ++j) { ev[j] = (float)a0[j]; ev[8 + j] = (float)a1[j]; }
#pragma unroll
    for (int k = 0; k < 16; ++k) {
      const float* wr = W + (kc * 16 + k) * HID;
      float ek = ev[k];
#pragma unroll
      for (int c = 0; c < HID; ++c) z[c] = fmaf(ek, wr[c], z[c]);
    }
  }
  union { __half h[8]; float4 f; } u;
  float4* yr = (float4*)(Y + (long)r * HID);
#pragma unroll
  for (int g = 0; g < 8; ++g) {
#pragma unroll
    for (int j = 0; j < 8; ++j) u.h[j] = __float2half(z[g * 8 + j]);
    yr[g] = u.f;
  }
}

// ---------------- CSR aggregation, quarter-wave per edge ----------------
// one wave per node; 16 lanes per edge (half4 = 4 channels/lane, 8B loads);
// 4 slots unrolled -> 16 edges in flight per iteration.
__global__ __launch_bounds__(256) void k_agg_csr(
    const __half* __restrict__ Hf, const float* __restrict__ dis,
    const int* __restrict__ rowoff, const int* __restrict__ csr_src,
    const float* __restrict__ b, __half* __restrict__ A, int n, int E, int relu) {
  int node = blockIdx.x * 4 + (threadIdx.x >> 6);
  if (node >= n) return;
  int L = threadIdx.x & 63;
  int sub = L >> 4;   // quarter id (which edge of 4)
  int cq = L & 15;    // channel quad: channels 4cq..4cq+3
  const half4* H4 = (const half4*)Hf;  // 16 half4 chunks per 64-ch row
  float dd = dis[node];
  int i0 = rowoff[node];
  int end = (node == n - 1) ? E : rowoff[node + 1];

  float z0[4] = {0.f, 0.f, 0.f, 0.f}, z1[4] = {0.f, 0.f, 0.f, 0.f};
  float z2[4] = {0.f, 0.f, 0.f, 0.f}, z3[4] = {0.f, 0.f, 0.f, 0.f};
  if (sub == 0) {  // self-loop term once
    half4 hv = H4[(long)node * 16 + cq];
    float w = dd * dd;
#pragma unroll
    for (int j = 0; j < 4; ++j) z0[j] = (float)hv[j] * w;
  }

  int last = end - 1;
  for (int base = i0; base < end; base += 16) {
    float* zp[4] = {z0, z1, z2, z3};
#pragma unroll
    for (int slot = 0; slot < 4; ++slot) {
      int idx = base + slot * 4 + sub;
      int idxc = min(idx, last);
      int s = csr_src[idxc];
      float w = (idx < end) ? dis[s] * dd : 0.f;
      half4 hv = H4[(long)s * 16 + cq];
      float* z = zp[slot];
#pragma unroll
      for (int j = 0; j < 4; ++j) z[j] = fmaf((float)hv[j], w, z[j]);
    }
  }

  float a[4];
#pragma unroll
  for (int j = 0; j < 4; ++j) {
    a[j] = (z0[j] + z1[j]) + (z2[j] + z3[j]);
    a[j] += __shfl_xor(a[j], 16, 64);
    a[j] += __shfl_xor(a[j], 32, 64);
  }
  if (sub == 0) {
    float4 bb = ((const float4*)b)[cq];
    float v0 = a[0] + bb.x, v1 = a[1] + bb.y, v2 = a[2] + bb.z, v3 = a[3] + bb.w;
    if (relu) {
      v0 = fmaxf(v0, 0.f); v1 = fmaxf(v1, 0.f);
      v2 = fmaxf(v2, 0.f); v3 = fmaxf(v3, 0.f);
    }
    half4 o = {(_Float16)v0, (_Float16)v1, (_Float16)v2, (_Float16)v3};
    ((half4*)A)[(long)node * 16 + cq] = o;
  }
}

// ---------------- edge classifier via f16 MFMA ----------------
__global__ __launch_bounds__(256) void k_classifier_mfma(
    const __half* __restrict__ Hf, const int* __restrict__ src,
    const int* __restrict__ dst, const __half* __restrict__ pack,
    const float* __restrict__ bc1, const float* __restrict__ Wc2,
    const float* __restrict__ bc2, float* __restrict__ out, int E, int ntiles,
    int nwaves) {
  int wid = blockIdx.x * 4 + (threadIdx.x >> 6);
  int L = threadIdx.x & 63;
  int m16 = L & 15, quad = L >> 4;

  half8 Bf[16];
  const half8* packv = (const half8*)pack;
#pragma unroll
  for (int f = 0; f < 16; ++f) Bf[f] = packv[f * 64 + L];

  float bc1v[4], w20[4], w21[4];
#pragma unroll
  for (int nb = 0; nb < 4; ++nb) {
    int n = m16 + 16 * nb;
    bc1v[nb] = bc1[n];
    w20[nb] = Wc2[2 * n];
    w21[nb] = Wc2[2 * n + 1];
  }
  float ob0 = bc2[0], ob1 = bc2[1];

  const half8* Hv = (const half8*)Hf;
  for (int t = wid; t < ntiles; t += nwaves) {
    int e = t * 16 + m16;
    int ec = min(e, E - 1);
    int s = src[ec], d = dst[ec];
    half8 A0 = Hv[(long)s * 8 + quad];
    half8 A1 = Hv[(long)s * 8 + 4 + quad];
    half8 A2 = Hv[(long)d * 8 + quad];
    half8 A3 = Hv[(long)d * 8 + 4 + quad];
    f32x4 acc[4] = {{0.f, 0.f, 0.f, 0.f},
                    {0.f, 0.f, 0.f, 0.f},
                    {0.f, 0.f, 0.f, 0.f},
                    {0.f, 0.f, 0.f, 0.f}};
#pragma unroll
    for (int nb = 0; nb < 4; ++nb) {
      acc[nb] = __builtin_amdgcn_mfma_f32_16x16x32_f16(A0, Bf[0 * 4 + nb], acc[nb], 0, 0, 0);
      acc[nb] = __builtin_amdgcn_mfma_f32_16x16x32_f16(A1, Bf[1 * 4 + nb], acc[nb], 0, 0, 0);
      acc[nb] = __builtin_amdgcn_mfma_f32_16x16x32_f16(A2, Bf[2 * 4 + nb], acc[nb], 0, 0, 0);
      acc[nb] = __builtin_amdgcn_mfma_f32_16x16x32_f16(A3, Bf[3 * 4 + nb], acc[nb], 0, 0, 0);
    }
    float o0[4] = {0.f, 0.f, 0.f, 0.f}, o1[4] = {0.f, 0.f, 0.f, 0.f};
#pragma unroll
    for (int nb = 0; nb < 4; ++nb) {
#pragma unroll
      for (int r = 0; r < 4; ++r) {
        float v = fmaxf(acc[nb][r] + bc1v[nb], 0.f);
        o0[r] = fmaf(v, w20[nb], o0[r]);
        o1[r] = fmaf(v, w21[nb], o1[r]);
      }
    }
#pragma unroll
    for (int mask = 1; mask < 16; mask <<= 1) {
#pragma unroll
      for (int r = 0; r < 4; ++r) {
        o0[r] += __shfl_xor(o0[r], mask, 64);
        o1[r] += __shfl_xor(o1[r], mask, 64);
      }
    }
    if (m16 < 4) {
      int ee = t * 16 + quad * 4 + m16;
      if (ee < E) {
        float2 o = {o0[m16] + ob0, o1[m16] + ob1};
        *(float2*)(out + 2 * (long)ee) = o;
      }
    }
  }
}

// ---------------- launch ----------------
extern "C" void kernel_launch(void* const* d_in, const int* in_sizes, int n_in,
                              void* d_out, int out_size, void* d_ws, size_t ws_size,
                              hipStream_t stream) {
  const float* x   = (const float*)d_in[0];
  const int*   ei  = (const int*)d_in[1];
  const float* W1  = (const float*)d_in[2];
  const float* b1  = (const float*)d_in[3];
  const float* W2  = (const float*)d_in[4];
  const float* b2  = (const float*)d_in[5];
  const float* Wc1 = (const float*)d_in[6];
  const float* bc1 = (const float*)d_in[7];
  const float* Wc2 = (const float*)d_in[8];
  const float* bc2 = (const float*)d_in[9];

  const int N = in_sizes[0] / 128;
  const int E = in_sizes[1] / 2;
  const int* src = ei;
  const int* dst = ei + E;

  // workspace layout
  float* dis    = (float*)d_ws;                    // N f32
  __half* pack  = (__half*)(dis + N);              // 8192 f16
  __half* y     = pack + 8192;                     // N*64 f16 (aliased by rank during CSR build)
  __half* h     = y + (long)N * HID;               // N*64 f16
  int* degi     = (int*)(h + (long)N * HID);       // N
  int* scanout  = degi + N;                        // N
  int* rowoff   = scanout + N;                     // N
  int* blocksums= rowoff + N;                      // 128
  int* csr_src  = blocksums + 128;                 // E
  int* rank     = (int*)y;  // E ints <= N*64 f16 bytes; dead once y is written

  const int B = 256;
  int gN = (N + B - 1) / B;
  int gE = (E + B - 1) / B;
  int nb = (N + 1023) / 1024;

  // ---- CSR build ----
  hipMemsetAsync(degi, 0, (size_t)N * sizeof(int), stream);
  k_count_rank<<<gE, B, 0, stream>>>(dst, degi, rank, E);
  k_scan1<<<nb, B, 0, stream>>>(degi, scanout, blocksums, dis, N);
  k_scan2<<<1, 128, 0, stream>>>(blocksums, nb);
  k_scan3<<<gN, B, 0, stream>>>(scanout, blocksums, rowoff, N);
  k_scatter_det<<<gE, B, 0, stream>>>(src, dst, rowoff, rank, csr_src, E);
  k_pack_wc1<<<4, B, 0, stream>>>(Wc1, pack);

  int gAgg = (N + 3) / 4;

  // ---- layer 1 ----
  k_lin_f32in<<<gN, B, 0, stream>>>(x, W1, y, N);
  k_agg_csr<<<gAgg, B, 0, stream>>>(y, dis, rowoff, csr_src, b1, h, N, E, 1);

  // ---- layer 2 ----
  k_lin_f16in<<<gN, B, 0, stream>>>(h, W2, y, N);
  k_agg_csr<<<gAgg, B, 0, stream>>>(y, dis, rowoff, csr_src, b2, h, N, E, 0);

  // ---- edge classifier ----
  int ntiles = (E + 15) / 16;
  int cblocks = 2048;
  int nwaves = cblocks * 4;
  k_classifier_mfma<<<cblocks, B, 0, stream>>>(h, src, dst, pack, bc1, Wc2, bc2,
                                               (float*)d_out, E, ntiles, nwaves);
}